// Round 2
// baseline (531.934 us; speedup 1.0000x reference)
//
#include <hip/hip_runtime.h>
#include <hip/hip_bf16.h>

#define ALPHA_ 0.2f
#define NEG_ -9e15f

typedef __attribute__((ext_vector_type(8))) short short8;
typedef __attribute__((ext_vector_type(4))) short short4v;
typedef __attribute__((ext_vector_type(4))) float f32x4;
typedef __hip_bfloat16 bf16;

__device__ __forceinline__ float lrelu(float x) { return x > 0.f ? x : ALPHA_ * x; }
__device__ __forceinline__ float eluf(float x) { return x > 0.f ? x : expf(x) - 1.f; }
__device__ __forceinline__ unsigned short f2bu(float x) {
  bf16 h = __float2bfloat16(x);
  return *reinterpret_cast<unsigned short*>(&h);
}

// ---------------- convert f32 -> bf16, 4 elems/thread -----------------------
__global__ void k_cvt(const float* __restrict__ src, unsigned short* __restrict__ dst,
                      long n4) {
  long id = (long)blockIdx.x * 256 + threadIdx.x;
  if (id >= n4) return;
  float4 v = ((const float4*)src)[id];
  short4v o;
  o.x = (short)f2bu(v.x); o.y = (short)f2bu(v.y);
  o.z = (short)f2bu(v.z); o.w = (short)f2bu(v.w);
  ((short4v*)dst)[id] = o;
}

// ---------------- transpose + convert: dst[c*R+r] = bf16(src[r*C+c]) --------
__global__ void k_cvtT(const float* __restrict__ src, unsigned short* __restrict__ dst,
                       int R, int C) {
  long id = (long)blockIdx.x * 256 + threadIdx.x;
  if (id >= (long)R * C) return;
  int c = (int)(id / R), r = (int)(id % R);
  dst[id] = f2bu(src[(size_t)r * C + c]);
}

// ---------------- K1: av gather + Wh = av @ W_gat, s1, s2 -------------------
// grid: B*N blocks (b*512+n), 256 threads
__global__ __launch_bounds__(256) void k_gat_wh(
    const int* __restrict__ atoms, const float* __restrict__ emb_atom,
    const float* __restrict__ W_gat, const float* __restrict__ a_gat,
    float* __restrict__ Wh, float* __restrict__ s1, float* __restrict__ s2) {
  int bn = blockIdx.x;
  int t = threadIdx.x;
  __shared__ float av[128];
  __shared__ float whl[256];
  int atom = atoms[bn];
  if (t < 128) av[t] = emb_atom[atom * 128 + t];
  __syncthreads();
  int h = t >> 6, f = t & 63;
  const float* Wg = W_gat + h * 128 * 64 + f;
  float acc = 0.f;
#pragma unroll 8
  for (int c = 0; c < 128; ++c) acc += av[c] * Wg[c * 64];
  whl[t] = acc;
  int b = bn >> 9, n = bn & 511;
  Wh[(((size_t)b * 4 + h) * 512 + n) * 64 + f] = acc;
  __syncthreads();
  if (t < 8) {
    int hh = t >> 1, which = t & 1;
    float s = 0.f;
    for (int ff = 0; ff < 64; ++ff)
      s += whl[hh * 64 + ff] * a_gat[hh * 128 + which * 64 + ff];
    size_t sidx = ((size_t)b * 4 + hh) * 512 + n;
    if (which == 0) s1[sidx] = s; else s2[sidx] = s;
  }
}

// ---------------- K2: head attention softmax + hp = att@Wh, elu -> multi ----
// grid: B*H*(N/8) = 4096 blocks (b*256 + h*64 + g), 256 threads
__global__ __launch_bounds__(256) void k_attn1(
    const int* __restrict__ adj, const float* __restrict__ Wh,
    const float* __restrict__ s1, const float* __restrict__ s2,
    float* __restrict__ multi) {
  int blk = blockIdx.x;
  int g = blk & 63;
  int h = (blk >> 6) & 3;
  int b = blk >> 8;
  int t = threadIdx.x;
  int lane = t & 63, wid = t >> 6;
  __shared__ float att[8 * 512];
  __shared__ float red[4];
  int n0 = g * 8;
  size_t bh = ((size_t)b * 4 + h) * 512;
  const int* adjb = adj + (size_t)b * 512 * 512;

  for (int r = 0; r < 8; ++r) {
    int n = n0 + r;
    float s1v = s1[bh + n];
    int ma = t, mb = t + 256;
    float e0 = lrelu(s1v + s2[bh + ma]);
    if (adjb[(size_t)n * 512 + ma] <= 0) e0 = NEG_;
    float e1 = lrelu(s1v + s2[bh + mb]);
    if (adjb[(size_t)n * 512 + mb] <= 0) e1 = NEG_;
    float mx = fmaxf(e0, e1);
#pragma unroll
    for (int o = 32; o > 0; o >>= 1) mx = fmaxf(mx, __shfl_down(mx, o));
    __syncthreads();
    if (lane == 0) red[wid] = mx;
    __syncthreads();
    mx = fmaxf(fmaxf(red[0], red[1]), fmaxf(red[2], red[3]));
    float x0 = expf(e0 - mx), x1 = expf(e1 - mx);
    float sm = x0 + x1;
#pragma unroll
    for (int o = 32; o > 0; o >>= 1) sm += __shfl_down(sm, o);
    __syncthreads();
    if (lane == 0) red[wid] = sm;
    __syncthreads();
    float inv = 1.f / (red[0] + red[1] + red[2] + red[3]);
    att[r * 512 + ma] = x0 * inv;
    att[r * 512 + mb] = x1 * inv;
  }
  __syncthreads();
  int f = t & 63, rq = t >> 6;  // handles rows rq and rq+4
  float a0 = 0.f, a1 = 0.f;
  const float* whb = Wh + bh * 64 + f;
#pragma unroll 8
  for (int m = 0; m < 512; ++m) {
    float wv = whb[(size_t)m * 64];
    a0 += att[rq * 512 + m] * wv;
    a1 += att[(rq + 4) * 512 + m] * wv;
  }
  size_t mbase = ((size_t)b * 512 + n0) * 256 + h * 64 + f;
  multi[mbase + (size_t)rq * 256] = eluf(a0);
  multi[mbase + (size_t)(rq + 4) * 256] = eluf(a1);
}

// ---------------- K3: Wh2 = multi @ W_out, s1b, s2b --------------------------
// grid: B*N blocks, 128 threads
__global__ __launch_bounds__(128) void k_wh2(
    const float* __restrict__ multi, const float* __restrict__ W_out,
    const float* __restrict__ a_out, float* __restrict__ Wh2,
    float* __restrict__ s1b, float* __restrict__ s2b) {
  int bn = blockIdx.x;
  int t = threadIdx.x;
  __shared__ float mrow[256];
  __shared__ float wrow[128];
  mrow[t] = multi[(size_t)bn * 256 + t];
  mrow[t + 128] = multi[(size_t)bn * 256 + t + 128];
  __syncthreads();
  float acc = 0.f;
  const float* W = W_out + t;
#pragma unroll 8
  for (int k = 0; k < 256; ++k) acc += mrow[k] * W[(size_t)k * 128];
  wrow[t] = acc;
  Wh2[(size_t)bn * 128 + t] = acc;
  __syncthreads();
  if (t < 2) {
    float s = 0.f;
    for (int ff = 0; ff < 128; ++ff) s += wrow[ff] * a_out[t * 128 + ff];
    if (t == 0) s1b[bn] = s; else s2b[bn] = s;
  }
}

// ---------------- K4: out-layer attention + elu + Wc epilogue -> d_out ------
// grid: B*(N/8) = 1024 blocks (b*64+g), 256 threads
__global__ __launch_bounds__(256) void k_attn2(
    const int* __restrict__ adj, const float* __restrict__ Wh2,
    const float* __restrict__ s1b, const float* __restrict__ s2b,
    const float* __restrict__ Wc, const float* __restrict__ bc,
    float* __restrict__ out) {
  int blk = blockIdx.x;
  int g = blk & 63, b = blk >> 6;
  int t = threadIdx.x, lane = t & 63, wid = t >> 6;
  __shared__ float att[8 * 512];
  __shared__ float red[4];
  __shared__ float orow[8 * 128];
  int n0 = g * 8;
  size_t bb = (size_t)b * 512;
  const int* adjb = adj + (size_t)b * 512 * 512;

  for (int r = 0; r < 8; ++r) {
    int n = n0 + r;
    float s1v = s1b[bb + n];
    int ma = t, mb = t + 256;
    float e0 = lrelu(s1v + s2b[bb + ma]);
    if (adjb[(size_t)n * 512 + ma] <= 0) e0 = NEG_;
    float e1 = lrelu(s1v + s2b[bb + mb]);
    if (adjb[(size_t)n * 512 + mb] <= 0) e1 = NEG_;
    float mx = fmaxf(e0, e1);
#pragma unroll
    for (int o = 32; o > 0; o >>= 1) mx = fmaxf(mx, __shfl_down(mx, o));
    __syncthreads();
    if (lane == 0) red[wid] = mx;
    __syncthreads();
    mx = fmaxf(fmaxf(red[0], red[1]), fmaxf(red[2], red[3]));
    float x0 = expf(e0 - mx), x1 = expf(e1 - mx);
    float sm = x0 + x1;
#pragma unroll
    for (int o = 32; o > 0; o >>= 1) sm += __shfl_down(sm, o);
    __syncthreads();
    if (lane == 0) red[wid] = sm;
    __syncthreads();
    float inv = 1.f / (red[0] + red[1] + red[2] + red[3]);
    att[r * 512 + ma] = x0 * inv;
    att[r * 512 + mb] = x1 * inv;
  }
  __syncthreads();
  int f = t & 127, rh = t >> 7;  // rows rh, rh+2, rh+4, rh+6
  float a0 = 0.f, a1 = 0.f, a2 = 0.f, a3 = 0.f;
  const float* wb = Wh2 + bb * 128 + f;
#pragma unroll 4
  for (int m = 0; m < 512; ++m) {
    float wv = wb[(size_t)m * 128];
    a0 += att[(rh + 0) * 512 + m] * wv;
    a1 += att[(rh + 2) * 512 + m] * wv;
    a2 += att[(rh + 4) * 512 + m] * wv;
    a3 += att[(rh + 6) * 512 + m] * wv;
  }
  orow[(rh + 0) * 128 + f] = eluf(a0);
  orow[(rh + 2) * 128 + f] = eluf(a1);
  orow[(rh + 4) * 128 + f] = eluf(a2);
  orow[(rh + 6) * 128 + f] = eluf(a3);
  __syncthreads();
  float bcf = bc[f];
  float c0 = 0.f, c1 = 0.f, c2 = 0.f, c3 = 0.f;
  const float* wcc = Wc + f;
#pragma unroll 4
  for (int k = 0; k < 128; ++k) {
    float wv = wcc[(size_t)k * 128];
    c0 += orow[(rh + 0) * 128 + k] * wv;
    c1 += orow[(rh + 2) * 128 + k] * wv;
    c2 += orow[(rh + 4) * 128 + k] * wv;
    c3 += orow[(rh + 6) * 128 + k] * wv;
  }
  size_t ob = ((size_t)b * 1536 + n0) * 128 + f;
  out[ob + (size_t)(rh + 0) * 128] = lrelu(c0 + bcf);
  out[ob + (size_t)(rh + 2) * 128] = lrelu(c1 + bcf);
  out[ob + (size_t)(rh + 4) * 128] = lrelu(c2 + bcf);
  out[ob + (size_t)(rh + 6) * 128] = lrelu(c3 + bcf);
}

// ---------------- MFMA GEMM: C = act(A @ Bt^T + bias) -----------------------
// A: M x K bf16 row-major; Bt: N x K bf16 row-major (pre-transposed weight).
// Wave computes a 32x32 tile. EPI 0: relu -> bf16 hidp (ld N).
// EPI 1: lrelu -> f32 d_out amino section with (b,l) remap.
template <int EPI>
__global__ __launch_bounds__(256) void k_gemm(
    const bf16* __restrict__ A, const bf16* __restrict__ Bt,
    const float* __restrict__ bias, void* __restrict__ outv,
    int M, int N, int K) {
  int wave = (blockIdx.x << 2) | (threadIdx.x >> 6);
  int lane = threadIdx.x & 63;
  int tnc = N >> 5;
  int tm = wave / tnc, tn = wave - tm * tnc;
  int m0 = tm << 5, n0 = tn << 5;
  if (m0 >= M) return;
  int row = lane & 15, quad = lane >> 4;
  const short8* Ap0 = (const short8*)(A + (size_t)(m0 + row) * K + quad * 8);
  const short8* Ap1 = (const short8*)(A + (size_t)(m0 + 16 + row) * K + quad * 8);
  const short8* Bp0 = (const short8*)(Bt + (size_t)(n0 + row) * K + quad * 8);
  const short8* Bp1 = (const short8*)(Bt + (size_t)(n0 + 16 + row) * K + quad * 8);
  f32x4 acc[2][2] = {{{0.f, 0.f, 0.f, 0.f}, {0.f, 0.f, 0.f, 0.f}},
                     {{0.f, 0.f, 0.f, 0.f}, {0.f, 0.f, 0.f, 0.f}}};
  int steps = K >> 5;
  for (int s = 0; s < steps; ++s) {
    short8 a0 = Ap0[s * 4];
    short8 a1 = Ap1[s * 4];
    short8 b0 = Bp0[s * 4];
    short8 b1 = Bp1[s * 4];
    acc[0][0] = __builtin_amdgcn_mfma_f32_16x16x32_bf16(a0, b0, acc[0][0], 0, 0, 0);
    acc[0][1] = __builtin_amdgcn_mfma_f32_16x16x32_bf16(a0, b1, acc[0][1], 0, 0, 0);
    acc[1][0] = __builtin_amdgcn_mfma_f32_16x16x32_bf16(a1, b0, acc[1][0], 0, 0, 0);
    acc[1][1] = __builtin_amdgcn_mfma_f32_16x16x32_bf16(a1, b1, acc[1][1], 0, 0, 0);
  }
  int col = lane & 15;
  float bv[2] = {bias[n0 + col], bias[n0 + 16 + col]};
#pragma unroll
  for (int i = 0; i < 2; ++i) {
#pragma unroll
    for (int j = 0; j < 2; ++j) {
#pragma unroll
      for (int r = 0; r < 4; ++r) {
        int m = m0 + i * 16 + quad * 4 + r;
        int n = n0 + j * 16 + col;
        float v = acc[i][j][r] + bv[j];
        if (EPI == 0) {
          v = v > 0.f ? v : 0.f;
          ((bf16*)outv)[(size_t)m * N + n] = __float2bfloat16(v);
        } else {
          v = lrelu(v);
          int b = m >> 10, l = m & 1023;
          ((float*)outv)[((size_t)b * 1536 + 512 + l) * 128 + n] = v;
        }
      }
    }
  }
}

extern "C" void kernel_launch(void* const* d_in, const int* in_sizes, int n_in,
                              void* d_out, int out_size, void* d_ws, size_t ws_size,
                              hipStream_t stream) {
  const int* atoms = (const int*)d_in[0];
  const int* adj = (const int*)d_in[1];
  const float* prot = (const float*)d_in[3];
  const float* emb_atom = (const float*)d_in[5];
  const float* W_gat = (const float*)d_in[6];
  const float* a_gat = (const float*)d_in[7];
  const float* W_out = (const float*)d_in[8];
  const float* a_out = (const float*)d_in[9];
  const float* Wc = (const float*)d_in[10];
  const float* bc = (const float*)d_in[11];
  const float* W1 = (const float*)d_in[12];
  const float* b1 = (const float*)d_in[13];
  const float* W2 = (const float*)d_in[14];
  const float* b2 = (const float*)d_in[15];
  float* out = (float*)d_out;

  char* p = (char*)d_ws;
  bf16* prot16 = (bf16*)p;    p += (size_t)16384 * 1152 * 2;          // 36 MB
  bf16* W1T = (bf16*)p;       p += (size_t)512 * 1152 * 2;            // 1.125 MB
  bf16* W2T = (bf16*)p;       p += (size_t)128 * 512 * 2;             // 128 KB
  bf16* hidp = (bf16*)p;      p += (size_t)16384 * 512 * 2;           // 16 MB
  float* Wh = (float*)p;      p += (size_t)16 * 4 * 512 * 64 * 4;     // 8 MB
  float* s1 = (float*)p;      p += 128 * 1024;
  float* s2 = (float*)p;      p += 128 * 1024;
  float* multi = (float*)p;   p += (size_t)16 * 512 * 256 * 4;        // 8 MB
  float* Wh2 = (float*)p;     p += (size_t)16 * 512 * 128 * 4;        // 4 MB
  float* s1b = (float*)p;     p += 64 * 1024;
  float* s2b = (float*)p;     p += 64 * 1024;

  // protein path: convert to bf16, then MFMA GEMMs
  long n4 = (long)16384 * 1152 / 4;
  k_cvt<<<(int)((n4 + 255) / 256), 256, 0, stream>>>(prot, (unsigned short*)prot16, n4);
  k_cvtT<<<(1152 * 512 + 255) / 256, 256, 0, stream>>>(W1, (unsigned short*)W1T, 1152, 512);
  k_cvtT<<<(512 * 128 + 255) / 256, 256, 0, stream>>>(W2, (unsigned short*)W2T, 512, 128);
  k_gemm<0><<<(16384 / 32) * (512 / 32) / 4, 256, 0, stream>>>(prot16, W1T, b1, hidp, 16384, 512, 1152);
  k_gemm<1><<<(16384 / 32) * (128 / 32) / 4, 256, 0, stream>>>(hidp, W2T, b2, out, 16384, 128, 512);

  // GAT path (f32 VALU)
  k_gat_wh<<<16 * 512, 256, 0, stream>>>(atoms, emb_atom, W_gat, a_gat, Wh, s1, s2);
  k_attn1<<<16 * 4 * 64, 256, 0, stream>>>(adj, Wh, s1, s2, multi);
  k_wh2<<<16 * 512, 128, 0, stream>>>(multi, W_out, a_out, Wh2, s1b, s2b);
  k_attn2<<<16 * 64, 256, 0, stream>>>(adj, Wh2, s1b, s2b, Wc, bc, out);

  (void)in_sizes; (void)n_in; (void)out_size; (void)ws_size;
}

// Round 3
// 434.445 us; speedup vs baseline: 1.2244x; 1.2244x over previous
//
#include <hip/hip_runtime.h>
#include <hip/hip_bf16.h>

#define ALPHA_ 0.2f
#define NEG_ -9e15f

typedef __attribute__((ext_vector_type(8))) short short8;
typedef __attribute__((ext_vector_type(4))) short short4v;
typedef __attribute__((ext_vector_type(4))) float f32x4;
typedef __hip_bfloat16 bf16;

__device__ __forceinline__ float lrelu(float x) { return x > 0.f ? x : ALPHA_ * x; }
__device__ __forceinline__ float eluf(float x) { return x > 0.f ? x : expf(x) - 1.f; }
__device__ __forceinline__ unsigned short f2bu(float x) {
  bf16 h = __float2bfloat16(x);
  return *reinterpret_cast<unsigned short*>(&h);
}
__device__ __forceinline__ void gload_lds16(const void* g, void* l) {
  __builtin_amdgcn_global_load_lds((const __attribute__((address_space(1))) void*)g,
                                   (__attribute__((address_space(3))) void*)l,
                                   16, 0, 0);
}

// ---------------- convert f32 -> bf16, 4 elems/thread -----------------------
__global__ void k_cvt(const float* __restrict__ src, unsigned short* __restrict__ dst,
                      long n4) {
  long id = (long)blockIdx.x * 256 + threadIdx.x;
  if (id >= n4) return;
  float4 v = ((const float4*)src)[id];
  short4v o;
  o.x = (short)f2bu(v.x); o.y = (short)f2bu(v.y);
  o.z = (short)f2bu(v.z); o.w = (short)f2bu(v.w);
  ((short4v*)dst)[id] = o;
}

// ---------------- transpose + convert: dst[c*R+r] = bf16(src[r*C+c]) --------
__global__ void k_cvtT(const float* __restrict__ src, unsigned short* __restrict__ dst,
                       int R, int C) {
  long id = (long)blockIdx.x * 256 + threadIdx.x;
  if (id >= (long)R * C) return;
  int c = (int)(id / R), r = (int)(id % R);
  dst[id] = f2bu(src[(size_t)r * C + c]);
}

// ---------------- MFMA GEMM, m97 structure: 128x128 tile, BK=32 -------------
// A: M x K bf16 row-major; Bt: N x K bf16 row-major (pre-transposed weight).
// 256 threads = 4 waves in 2x2; each wave computes 64x64 via 4x4 of 16x16x32.
// EPI 0: relu -> bf16 out (ld N). EPI 1: lrelu -> f32 d_out amino remap.
template <int EPI>
__global__ __launch_bounds__(256) void k_gemm_lds(
    const bf16* __restrict__ A, const bf16* __restrict__ Bt,
    const float* __restrict__ bias, void* __restrict__ outv,
    int M, int N, int K) {
  __shared__ bf16 sA[128 * 32];
  __shared__ bf16 sB[128 * 32];
  int t = threadIdx.x;
  int w = t >> 6, lane = t & 63;
  int ntiles = N >> 7;
  int tm = blockIdx.x / ntiles, tn = blockIdx.x - tm * ntiles;
  int m0 = tm << 7, n0 = tn << 7;
  // staging: chunk c handles LDS bytes [c*16, c*16+16) == row c>>2, k-chunk c&3.
  // thread t issues chunks t and t+256 (wave-contiguous: base + lane*16).
  int r0 = t >> 2, cc = t & 3;
  const bf16* ga0 = A + (size_t)(m0 + r0) * K + cc * 8;
  const bf16* ga1 = A + (size_t)(m0 + r0 + 64) * K + cc * 8;
  const bf16* gb0 = Bt + (size_t)(n0 + r0) * K + cc * 8;
  const bf16* gb1 = Bt + (size_t)(n0 + r0 + 64) * K + cc * 8;
  bf16* la0 = sA + (size_t)t * 8;
  bf16* la1 = sA + (size_t)(t + 256) * 8;
  bf16* lb0 = sB + (size_t)t * 8;
  bf16* lb1 = sB + (size_t)(t + 256) * 8;

  int wm = (w >> 1) << 6, wn = (w & 1) << 6;
  int row = lane & 15, quad = lane >> 4;
  f32x4 acc[4][4];
#pragma unroll
  for (int i = 0; i < 4; ++i)
#pragma unroll
    for (int j = 0; j < 4; ++j) acc[i][j] = (f32x4){0.f, 0.f, 0.f, 0.f};

  int steps = K >> 5;
  for (int s = 0; s < steps; ++s) {
    __syncthreads();  // previous compute done before LDS overwrite
    int ko = s << 5;
    gload_lds16(ga0 + ko, la0);
    gload_lds16(ga1 + ko, la1);
    gload_lds16(gb0 + ko, lb0);
    gload_lds16(gb1 + ko, lb1);
    __syncthreads();  // drains vmcnt: tiles resident
    short8 af[4], bf[4];
#pragma unroll
    for (int i = 0; i < 4; ++i)
      af[i] = *(const short8*)(sA + (size_t)(wm + i * 16 + row) * 32 + quad * 8);
#pragma unroll
    for (int j = 0; j < 4; ++j)
      bf[j] = *(const short8*)(sB + (size_t)(wn + j * 16 + row) * 32 + quad * 8);
#pragma unroll
    for (int i = 0; i < 4; ++i)
#pragma unroll
      for (int j = 0; j < 4; ++j)
        acc[i][j] = __builtin_amdgcn_mfma_f32_16x16x32_bf16(af[i], bf[j], acc[i][j], 0, 0, 0);
  }

  int col = lane & 15;
#pragma unroll
  for (int j = 0; j < 4; ++j) {
    int n = n0 + wn + j * 16 + col;
    float bv = bias[n];
#pragma unroll
    for (int i = 0; i < 4; ++i) {
#pragma unroll
      for (int r = 0; r < 4; ++r) {
        int m = m0 + wm + i * 16 + quad * 4 + r;
        float v = acc[i][j][r] + bv;
        if (EPI == 0) {
          v = v > 0.f ? v : 0.f;
          ((bf16*)outv)[(size_t)m * N + n] = __float2bfloat16(v);
        } else {
          v = lrelu(v);
          int b = m >> 10, l = m & 1023;
          ((float*)outv)[((size_t)b * 1536 + 512 + l) * 128 + n] = v;
        }
      }
    }
  }
}

// ---------------- K1: av gather + Wh = av @ W_gat, s1, s2 -------------------
__global__ __launch_bounds__(256) void k_gat_wh(
    const int* __restrict__ atoms, const float* __restrict__ emb_atom,
    const float* __restrict__ W_gat, const float* __restrict__ a_gat,
    float* __restrict__ Wh, float* __restrict__ s1, float* __restrict__ s2) {
  int bn = blockIdx.x;
  int t = threadIdx.x;
  __shared__ float av[128];
  __shared__ float whl[256];
  int atom = atoms[bn];
  if (t < 128) av[t] = emb_atom[atom * 128 + t];
  __syncthreads();
  int h = t >> 6, f = t & 63;
  const float* Wg = W_gat + h * 128 * 64 + f;
  float acc = 0.f;
#pragma unroll 8
  for (int c = 0; c < 128; ++c) acc += av[c] * Wg[c * 64];
  whl[t] = acc;
  int b = bn >> 9, n = bn & 511;
  Wh[(((size_t)b * 4 + h) * 512 + n) * 64 + f] = acc;
  __syncthreads();
  if (t < 8) {
    int hh = t >> 1, which = t & 1;
    float s = 0.f;
    for (int ff = 0; ff < 64; ++ff)
      s += whl[hh * 64 + ff] * a_gat[hh * 128 + which * 64 + ff];
    size_t sidx = ((size_t)b * 4 + hh) * 512 + n;
    if (which == 0) s1[sidx] = s; else s2[sidx] = s;
  }
}

// ---------------- K2: head attention softmax + hp = att@Wh, elu -> multi ----
__global__ __launch_bounds__(256) void k_attn1(
    const int* __restrict__ adj, const float* __restrict__ Wh,
    const float* __restrict__ s1, const float* __restrict__ s2,
    float* __restrict__ multi) {
  int blk = blockIdx.x;
  int g = blk & 63;
  int h = (blk >> 6) & 3;
  int b = blk >> 8;
  int t = threadIdx.x;
  int lane = t & 63, wid = t >> 6;
  __shared__ float att[8 * 512];
  __shared__ float red[4];
  int n0 = g * 8;
  size_t bh = ((size_t)b * 4 + h) * 512;
  const int* adjb = adj + (size_t)b * 512 * 512;

  for (int r = 0; r < 8; ++r) {
    int n = n0 + r;
    float s1v = s1[bh + n];
    int ma = t, mb = t + 256;
    float e0 = lrelu(s1v + s2[bh + ma]);
    if (adjb[(size_t)n * 512 + ma] <= 0) e0 = NEG_;
    float e1 = lrelu(s1v + s2[bh + mb]);
    if (adjb[(size_t)n * 512 + mb] <= 0) e1 = NEG_;
    float mx = fmaxf(e0, e1);
#pragma unroll
    for (int o = 32; o > 0; o >>= 1) mx = fmaxf(mx, __shfl_down(mx, o));
    __syncthreads();
    if (lane == 0) red[wid] = mx;
    __syncthreads();
    mx = fmaxf(fmaxf(red[0], red[1]), fmaxf(red[2], red[3]));
    float x0 = expf(e0 - mx), x1 = expf(e1 - mx);
    float sm = x0 + x1;
#pragma unroll
    for (int o = 32; o > 0; o >>= 1) sm += __shfl_down(sm, o);
    __syncthreads();
    if (lane == 0) red[wid] = sm;
    __syncthreads();
    float inv = 1.f / (red[0] + red[1] + red[2] + red[3]);
    att[r * 512 + ma] = x0 * inv;
    att[r * 512 + mb] = x1 * inv;
  }
  __syncthreads();
  int f = t & 63, rq = t >> 6;  // handles rows rq and rq+4
  float a0 = 0.f, a1 = 0.f;
  const float* whb = Wh + bh * 64 + f;
#pragma unroll 8
  for (int m = 0; m < 512; ++m) {
    float wv = whb[(size_t)m * 64];
    a0 += att[rq * 512 + m] * wv;
    a1 += att[(rq + 4) * 512 + m] * wv;
  }
  size_t mbase = ((size_t)b * 512 + n0) * 256 + h * 64 + f;
  multi[mbase + (size_t)rq * 256] = eluf(a0);
  multi[mbase + (size_t)(rq + 4) * 256] = eluf(a1);
}

// ---------------- K3: Wh2 = multi @ W_out, s1b, s2b --------------------------
__global__ __launch_bounds__(128) void k_wh2(
    const float* __restrict__ multi, const float* __restrict__ W_out,
    const float* __restrict__ a_out, float* __restrict__ Wh2,
    float* __restrict__ s1b, float* __restrict__ s2b) {
  int bn = blockIdx.x;
  int t = threadIdx.x;
  __shared__ float mrow[256];
  __shared__ float wrow[128];
  mrow[t] = multi[(size_t)bn * 256 + t];
  mrow[t + 128] = multi[(size_t)bn * 256 + t + 128];
  __syncthreads();
  float acc = 0.f;
  const float* W = W_out + t;
#pragma unroll 8
  for (int k = 0; k < 256; ++k) acc += mrow[k] * W[(size_t)k * 128];
  wrow[t] = acc;
  Wh2[(size_t)bn * 128 + t] = acc;
  __syncthreads();
  if (t < 2) {
    float s = 0.f;
    for (int ff = 0; ff < 128; ++ff) s += wrow[ff] * a_out[t * 128 + ff];
    if (t == 0) s1b[bn] = s; else s2b[bn] = s;
  }
}

// ---------------- K4: out-layer attention + elu + Wc epilogue -> d_out ------
__global__ __launch_bounds__(256) void k_attn2(
    const int* __restrict__ adj, const float* __restrict__ Wh2,
    const float* __restrict__ s1b, const float* __restrict__ s2b,
    const float* __restrict__ Wc, const float* __restrict__ bc,
    float* __restrict__ out) {
  int blk = blockIdx.x;
  int g = blk & 63, b = blk >> 6;
  int t = threadIdx.x, lane = t & 63, wid = t >> 6;
  __shared__ float att[8 * 512];
  __shared__ float red[4];
  __shared__ float orow[8 * 128];
  int n0 = g * 8;
  size_t bb = (size_t)b * 512;
  const int* adjb = adj + (size_t)b * 512 * 512;

  for (int r = 0; r < 8; ++r) {
    int n = n0 + r;
    float s1v = s1b[bb + n];
    int ma = t, mb = t + 256;
    float e0 = lrelu(s1v + s2b[bb + ma]);
    if (adjb[(size_t)n * 512 + ma] <= 0) e0 = NEG_;
    float e1 = lrelu(s1v + s2b[bb + mb]);
    if (adjb[(size_t)n * 512 + mb] <= 0) e1 = NEG_;
    float mx = fmaxf(e0, e1);
#pragma unroll
    for (int o = 32; o > 0; o >>= 1) mx = fmaxf(mx, __shfl_down(mx, o));
    __syncthreads();
    if (lane == 0) red[wid] = mx;
    __syncthreads();
    mx = fmaxf(fmaxf(red[0], red[1]), fmaxf(red[2], red[3]));
    float x0 = expf(e0 - mx), x1 = expf(e1 - mx);
    float sm = x0 + x1;
#pragma unroll
    for (int o = 32; o > 0; o >>= 1) sm += __shfl_down(sm, o);
    __syncthreads();
    if (lane == 0) red[wid] = sm;
    __syncthreads();
    float inv = 1.f / (red[0] + red[1] + red[2] + red[3]);
    att[r * 512 + ma] = x0 * inv;
    att[r * 512 + mb] = x1 * inv;
  }
  __syncthreads();
  int f = t & 127, rh = t >> 7;  // rows rh, rh+2, rh+4, rh+6
  float a0 = 0.f, a1 = 0.f, a2 = 0.f, a3 = 0.f;
  const float* wb = Wh2 + bb * 128 + f;
#pragma unroll 4
  for (int m = 0; m < 512; ++m) {
    float wv = wb[(size_t)m * 128];
    a0 += att[(rh + 0) * 512 + m] * wv;
    a1 += att[(rh + 2) * 512 + m] * wv;
    a2 += att[(rh + 4) * 512 + m] * wv;
    a3 += att[(rh + 6) * 512 + m] * wv;
  }
  orow[(rh + 0) * 128 + f] = eluf(a0);
  orow[(rh + 2) * 128 + f] = eluf(a1);
  orow[(rh + 4) * 128 + f] = eluf(a2);
  orow[(rh + 6) * 128 + f] = eluf(a3);
  __syncthreads();
  float bcf = bc[f];
  float c0 = 0.f, c1 = 0.f, c2 = 0.f, c3 = 0.f;
  const float* wcc = Wc + f;
#pragma unroll 4
  for (int k = 0; k < 128; ++k) {
    float wv = wcc[(size_t)k * 128];
    c0 += orow[(rh + 0) * 128 + k] * wv;
    c1 += orow[(rh + 2) * 128 + k] * wv;
    c2 += orow[(rh + 4) * 128 + k] * wv;
    c3 += orow[(rh + 6) * 128 + k] * wv;
  }
  size_t ob = ((size_t)b * 1536 + n0) * 128 + f;
  out[ob + (size_t)(rh + 0) * 128] = lrelu(c0 + bcf);
  out[ob + (size_t)(rh + 2) * 128] = lrelu(c1 + bcf);
  out[ob + (size_t)(rh + 4) * 128] = lrelu(c2 + bcf);
  out[ob + (size_t)(rh + 6) * 128] = lrelu(c3 + bcf);
}

extern "C" void kernel_launch(void* const* d_in, const int* in_sizes, int n_in,
                              void* d_out, int out_size, void* d_ws, size_t ws_size,
                              hipStream_t stream) {
  const int* atoms = (const int*)d_in[0];
  const int* adj = (const int*)d_in[1];
  const float* prot = (const float*)d_in[3];
  const float* emb_atom = (const float*)d_in[5];
  const float* W_gat = (const float*)d_in[6];
  const float* a_gat = (const float*)d_in[7];
  const float* W_out = (const float*)d_in[8];
  const float* a_out = (const float*)d_in[9];
  const float* Wc = (const float*)d_in[10];
  const float* bc = (const float*)d_in[11];
  const float* W1 = (const float*)d_in[12];
  const float* b1 = (const float*)d_in[13];
  const float* W2 = (const float*)d_in[14];
  const float* b2 = (const float*)d_in[15];
  float* out = (float*)d_out;

  char* p = (char*)d_ws;
  bf16* prot16 = (bf16*)p;    p += (size_t)16384 * 1152 * 2;          // 36 MB
  bf16* W1T = (bf16*)p;       p += (size_t)512 * 1152 * 2;            // 1.125 MB
  bf16* W2T = (bf16*)p;       p += (size_t)128 * 512 * 2;             // 128 KB
  bf16* hidp = (bf16*)p;      p += (size_t)16384 * 512 * 2;           // 16 MB
  float* Wh = (float*)p;      p += (size_t)16 * 4 * 512 * 64 * 4;     // 8 MB
  float* s1 = (float*)p;      p += 128 * 1024;
  float* s2 = (float*)p;      p += 128 * 1024;
  float* multi = (float*)p;   p += (size_t)16 * 512 * 256 * 4;        // 8 MB
  float* Wh2 = (float*)p;     p += (size_t)16 * 512 * 128 * 4;        // 4 MB
  float* s1b = (float*)p;     p += 64 * 1024;
  float* s2b = (float*)p;     p += 64 * 1024;

  // protein path: convert to bf16, then LDS-staged MFMA GEMMs
  long n4 = (long)16384 * 1152 / 4;
  k_cvt<<<(int)((n4 + 255) / 256), 256, 0, stream>>>(prot, (unsigned short*)prot16, n4);
  k_cvtT<<<(1152 * 512 + 255) / 256, 256, 0, stream>>>(W1, (unsigned short*)W1T, 1152, 512);
  k_cvtT<<<(512 * 128 + 255) / 256, 256, 0, stream>>>(W2, (unsigned short*)W2T, 512, 128);
  k_gemm_lds<0><<<(16384 / 128) * (512 / 128), 256, 0, stream>>>(prot16, W1T, b1, hidp, 16384, 512, 1152);
  k_gemm_lds<1><<<(16384 / 128) * (128 / 128), 256, 0, stream>>>(hidp, W2T, b2, out, 16384, 128, 512);

  // GAT path (f32 VALU)
  k_gat_wh<<<16 * 512, 256, 0, stream>>>(atoms, emb_atom, W_gat, a_gat, Wh, s1, s2);
  k_attn1<<<16 * 4 * 64, 256, 0, stream>>>(adj, Wh, s1, s2, multi);
  k_wh2<<<16 * 512, 128, 0, stream>>>(multi, W_out, a_out, Wh2, s1b, s2b);
  k_attn2<<<16 * 64, 256, 0, stream>>>(adj, Wh2, s1b, s2b, Wc, bc, out);

  (void)in_sizes; (void)n_in; (void)out_size; (void)ws_size;
}

// Round 4
// 282.705 us; speedup vs baseline: 1.8816x; 1.5367x over previous
//
#include <hip/hip_runtime.h>
#include <hip/hip_bf16.h>

#define ALPHA_ 0.2f
#define NEG_ -9e15f

typedef __attribute__((ext_vector_type(8))) short short8;
typedef __attribute__((ext_vector_type(4))) short short4v;
typedef __attribute__((ext_vector_type(4))) float f32x4;
typedef __hip_bfloat16 bf16;

__device__ __forceinline__ float lrelu(float x) { return x > 0.f ? x : ALPHA_ * x; }
__device__ __forceinline__ float eluf(float x) { return x > 0.f ? x : expf(x) - 1.f; }
__device__ __forceinline__ unsigned short f2bu(float x) {
  bf16 h = __float2bfloat16(x);
  return *reinterpret_cast<unsigned short*>(&h);
}
__device__ __forceinline__ float bu2f(unsigned short u) {
  bf16 h = *reinterpret_cast<bf16*>(&u);
  return __bfloat162float(h);
}
__device__ __forceinline__ void gload_lds16(const void* g, void* l) {
  __builtin_amdgcn_global_load_lds((const __attribute__((address_space(1))) void*)g,
                                   (__attribute__((address_space(3))) void*)l,
                                   16, 0, 0);
}

// ---------------- convert f32 -> bf16, 4 elems/thread -----------------------
__global__ void k_cvt(const float* __restrict__ src, unsigned short* __restrict__ dst,
                      long n4) {
  long id = (long)blockIdx.x * 256 + threadIdx.x;
  if (id >= n4) return;
  float4 v = ((const float4*)src)[id];
  short4v o;
  o.x = (short)f2bu(v.x); o.y = (short)f2bu(v.y);
  o.z = (short)f2bu(v.z); o.w = (short)f2bu(v.w);
  ((short4v*)dst)[id] = o;
}

// ---------------- transpose + convert: dst[c*R+r] = bf16(src[r*C+c]) --------
__global__ void k_cvtT(const float* __restrict__ src, unsigned short* __restrict__ dst,
                       int R, int C) {
  long id = (long)blockIdx.x * 256 + threadIdx.x;
  if (id >= (long)R * C) return;
  int c = (int)(id / R), r = (int)(id % R);
  dst[id] = f2bu(src[(size_t)r * C + c]);
}

// ---------------- MFMA GEMM, 128x128 tile, BK=32 (m97 structure) ------------
// A: M x K bf16 row-major; Bt: N x K bf16 row-major.
// EPI 0: relu -> bf16 out (ld N). EPI 1: lrelu -> f32 d_out amino remap.
template <int EPI>
__global__ __launch_bounds__(256) void k_gemm_lds(
    const bf16* __restrict__ A, const bf16* __restrict__ Bt,
    const float* __restrict__ bias, void* __restrict__ outv,
    int M, int N, int K) {
  __shared__ bf16 sA[128 * 32];
  __shared__ bf16 sB[128 * 32];
  int t = threadIdx.x;
  int w = t >> 6, lane = t & 63;
  int ntiles = N >> 7;
  int tm = blockIdx.x / ntiles, tn = blockIdx.x - tm * ntiles;
  int m0 = tm << 7, n0 = tn << 7;
  int r0 = t >> 2, cc = t & 3;
  const bf16* ga0 = A + (size_t)(m0 + r0) * K + cc * 8;
  const bf16* ga1 = A + (size_t)(m0 + r0 + 64) * K + cc * 8;
  const bf16* gb0 = Bt + (size_t)(n0 + r0) * K + cc * 8;
  const bf16* gb1 = Bt + (size_t)(n0 + r0 + 64) * K + cc * 8;
  bf16* la0 = sA + (size_t)t * 8;
  bf16* la1 = sA + (size_t)(t + 256) * 8;
  bf16* lb0 = sB + (size_t)t * 8;
  bf16* lb1 = sB + (size_t)(t + 256) * 8;

  int wm = (w >> 1) << 6, wn = (w & 1) << 6;
  int row = lane & 15, quad = lane >> 4;
  f32x4 acc[4][4];
#pragma unroll
  for (int i = 0; i < 4; ++i)
#pragma unroll
    for (int j = 0; j < 4; ++j) acc[i][j] = (f32x4){0.f, 0.f, 0.f, 0.f};

  int steps = K >> 5;
  for (int s = 0; s < steps; ++s) {
    __syncthreads();
    int ko = s << 5;
    gload_lds16(ga0 + ko, la0);
    gload_lds16(ga1 + ko, la1);
    gload_lds16(gb0 + ko, lb0);
    gload_lds16(gb1 + ko, lb1);
    __syncthreads();
    short8 af[4], bfr[4];
#pragma unroll
    for (int i = 0; i < 4; ++i)
      af[i] = *(const short8*)(sA + (size_t)(wm + i * 16 + row) * 32 + quad * 8);
#pragma unroll
    for (int j = 0; j < 4; ++j)
      bfr[j] = *(const short8*)(sB + (size_t)(wn + j * 16 + row) * 32 + quad * 8);
#pragma unroll
    for (int i = 0; i < 4; ++i)
#pragma unroll
      for (int j = 0; j < 4; ++j)
        acc[i][j] = __builtin_amdgcn_mfma_f32_16x16x32_bf16(af[i], bfr[j], acc[i][j], 0, 0, 0);
  }

  int col = lane & 15;
#pragma unroll
  for (int j = 0; j < 4; ++j) {
    int n = n0 + wn + j * 16 + col;
    float bv = bias[n];
#pragma unroll
    for (int i = 0; i < 4; ++i) {
#pragma unroll
      for (int r = 0; r < 4; ++r) {
        int m = m0 + wm + i * 16 + quad * 4 + r;
        float v = acc[i][j][r] + bv;
        if (EPI == 0) {
          v = v > 0.f ? v : 0.f;
          ((bf16*)outv)[(size_t)m * N + n] = __float2bfloat16(v);
        } else {
          v = lrelu(v);
          int b = m >> 10, l = m & 1023;
          ((float*)outv)[((size_t)b * 1536 + 512 + l) * 128 + n] = v;
        }
      }
    }
  }
}

// ---------------- k_tab: per-atom-type Wh table (45 types) ------------------
// grid 45 blocks, 256 threads (h = t>>6, f = t&63)
__global__ __launch_bounds__(256) void k_tab(
    const float* __restrict__ emb_atom, const float* __restrict__ W_gat,
    const float* __restrict__ a_gat, unsigned short* __restrict__ tab_wh,
    float* __restrict__ tab_s1, float* __restrict__ tab_s2) {
  int a = blockIdx.x;
  int t = threadIdx.x;
  __shared__ float av[128];
  __shared__ float whl[256];
  if (t < 128) av[t] = emb_atom[a * 128 + t];
  __syncthreads();
  int h = t >> 6, f = t & 63;
  const float* Wg = W_gat + h * 128 * 64 + f;
  float acc = 0.f;
#pragma unroll 8
  for (int c = 0; c < 128; ++c) acc += av[c] * Wg[c * 64];
  whl[t] = acc;
  tab_wh[a * 256 + t] = f2bu(acc);
  __syncthreads();
  if (t < 8) {
    int hh = t >> 1, which = t & 1;
    float s = 0.f;
    for (int ff = 0; ff < 64; ++ff)
      s += whl[hh * 64 + ff] * a_gat[hh * 128 + which * 64 + ff];
    if (which == 0) tab_s1[a * 4 + hh] = s; else tab_s2[a * 4 + hh] = s;
  }
}

// ---------------- k_gather: WhT[b,h,f,n], s1[b,h,n], s2 ---------------------
// grid 64 blocks (b*4+h), 256 threads
__global__ __launch_bounds__(256) void k_gather(
    const int* __restrict__ atoms, const unsigned short* __restrict__ tab_wh,
    const float* __restrict__ tab_s1, const float* __restrict__ tab_s2,
    unsigned short* __restrict__ WhT, float* __restrict__ s1,
    float* __restrict__ s2) {
  int bh = blockIdx.x;
  int b = bh >> 2, h = bh & 3;
  int t = threadIdx.x;
  __shared__ int atom_l[512];
  __shared__ unsigned short tabL[45 * 64];
  atom_l[t] = atoms[b * 512 + t];
  atom_l[t + 256] = atoms[b * 512 + t + 256];
  for (int i = t; i < 45 * 64; i += 256)
    tabL[i] = tab_wh[(i >> 6) * 256 + h * 64 + (i & 63)];
  __syncthreads();
  {
    int n = t;
    s1[(size_t)bh * 512 + n] = tab_s1[atom_l[n] * 4 + h];
    s2[(size_t)bh * 512 + n] = tab_s2[atom_l[n] * 4 + h];
    n = t + 256;
    s1[(size_t)bh * 512 + n] = tab_s1[atom_l[n] * 4 + h];
    s2[(size_t)bh * 512 + n] = tab_s2[atom_l[n] * 4 + h];
  }
  for (int f = 0; f < 64; ++f) {
    WhT[((size_t)bh * 64 + f) * 512 + t] = tabL[atom_l[t] * 64 + f];
    WhT[((size_t)bh * 64 + f) * 512 + t + 256] = tabL[atom_l[t + 256] * 64 + f];
  }
}

// ---------------- k_attn1_mfma: softmax + MFMA att@Wh -> multi (bf16) -------
// grid: b*64 + h*16 + rb (1024 blocks), 256 threads = 4 waves
#define ATTP 520  // padded att row stride (bf16 elems): 1040B, 16B-aligned
__global__ __launch_bounds__(256) void k_attn1_mfma(
    const int* __restrict__ adj, const unsigned short* __restrict__ WhT,
    const float* __restrict__ s1, const float* __restrict__ s2,
    unsigned short* __restrict__ multi_bf) {
  int blk = blockIdx.x;
  int rb = blk & 15, h = (blk >> 4) & 3, b = blk >> 6;
  int t = threadIdx.x, w = t >> 6, lane = t & 63;
  __shared__ unsigned short satt[32 * ATTP];
  int n0 = rb * 32;
  size_t bh = ((size_t)b * 4 + h) * 512;

  // phase 1: wave-local softmax, 8 rows per wave, 8 cols per lane
  float s2c[8];
  {
    const float4* sp = (const float4*)(s2 + bh + lane * 8);
    float4 v0 = sp[0], v1 = sp[1];
    s2c[0] = v0.x; s2c[1] = v0.y; s2c[2] = v0.z; s2c[3] = v0.w;
    s2c[4] = v1.x; s2c[5] = v1.y; s2c[6] = v1.z; s2c[7] = v1.w;
  }
  for (int rr = 0; rr < 8; ++rr) {
    int rl = w * 8 + rr;
    int n = n0 + rl;
    float s1v = s1[bh + n];
    const int* ap = adj + (size_t)b * 262144 + (size_t)n * 512 + lane * 8;
    int4 a0 = *(const int4*)ap;
    int4 a1 = *(const int4*)(ap + 4);
    float e[8];
    e[0] = a0.x > 0 ? lrelu(s1v + s2c[0]) : NEG_;
    e[1] = a0.y > 0 ? lrelu(s1v + s2c[1]) : NEG_;
    e[2] = a0.z > 0 ? lrelu(s1v + s2c[2]) : NEG_;
    e[3] = a0.w > 0 ? lrelu(s1v + s2c[3]) : NEG_;
    e[4] = a1.x > 0 ? lrelu(s1v + s2c[4]) : NEG_;
    e[5] = a1.y > 0 ? lrelu(s1v + s2c[5]) : NEG_;
    e[6] = a1.z > 0 ? lrelu(s1v + s2c[6]) : NEG_;
    e[7] = a1.w > 0 ? lrelu(s1v + s2c[7]) : NEG_;
    float mx = e[0];
#pragma unroll
    for (int k = 1; k < 8; ++k) mx = fmaxf(mx, e[k]);
#pragma unroll
    for (int o = 32; o > 0; o >>= 1) mx = fmaxf(mx, __shfl_xor(mx, o));
    float x[8], sm = 0.f;
#pragma unroll
    for (int k = 0; k < 8; ++k) { x[k] = expf(e[k] - mx); sm += x[k]; }
#pragma unroll
    for (int o = 32; o > 0; o >>= 1) sm += __shfl_xor(sm, o);
    float inv = 1.f / sm;
    short8 st;
#pragma unroll
    for (int k = 0; k < 8; ++k) st[k] = (short)f2bu(x[k] * inv);
    *(short8*)(satt + rl * ATTP + lane * 8) = st;
  }
  __syncthreads();

  // phase 2: MFMA. wave w -> f block w*16; rg 0..1 (rows 0-15 / 16-31)
  int row = lane & 15, quad = lane >> 4;
  int f0 = w * 16;
  f32x4 acc0 = {0.f, 0.f, 0.f, 0.f}, acc1 = {0.f, 0.f, 0.f, 0.f};
  const unsigned short* bp = WhT + (bh >> 9 << 9) / 8; // dummy avoid
  (void)bp;
  const unsigned short* wp = WhT + ((size_t)(b * 4 + h) * 64 + f0 + row) * 512 + quad * 8;
#pragma unroll
  for (int kk = 0; kk < 16; ++kk) {
    short8 bfr = *(const short8*)(wp + kk * 32);
    short8 af0 = *(const short8*)(satt + row * ATTP + kk * 32 + quad * 8);
    short8 af1 = *(const short8*)(satt + (16 + row) * ATTP + kk * 32 + quad * 8);
    acc0 = __builtin_amdgcn_mfma_f32_16x16x32_bf16(af0, bfr, acc0, 0, 0, 0);
    acc1 = __builtin_amdgcn_mfma_f32_16x16x32_bf16(af1, bfr, acc1, 0, 0, 0);
  }
  int col = lane & 15;
#pragma unroll
  for (int r = 0; r < 4; ++r) {
    int f = f0 + col;
    int m = n0 + quad * 4 + r;
    multi_bf[((size_t)b * 512 + m) * 256 + h * 64 + f] = f2bu(eluf(acc0[r]));
    m = n0 + 16 + quad * 4 + r;
    multi_bf[((size_t)b * 512 + m) * 256 + h * 64 + f] = f2bu(eluf(acc1[r]));
  }
}

// ---------------- k_wh2t: Wh2T = (multi @ W_out)^T bf16 ---------------------
// GEMM M=8192 N=128 K=256, LDS-transpose epilogue. grid 64 blocks.
#define TP 136
__global__ __launch_bounds__(256) void k_wh2t(
    const bf16* __restrict__ A, const bf16* __restrict__ Bt,
    unsigned short* __restrict__ Wh2T) {
  __shared__ bf16 sA[128 * 32];
  __shared__ bf16 sB[128 * 32];
  __shared__ unsigned short sT[128 * TP];
  const int K = 256;
  int t = threadIdx.x;
  int w = t >> 6, lane = t & 63;
  int m0 = blockIdx.x << 7;
  int r0 = t >> 2, cc = t & 3;
  const bf16* ga0 = A + (size_t)(m0 + r0) * K + cc * 8;
  const bf16* ga1 = A + (size_t)(m0 + r0 + 64) * K + cc * 8;
  const bf16* gb0 = Bt + (size_t)r0 * K + cc * 8;
  const bf16* gb1 = Bt + (size_t)(r0 + 64) * K + cc * 8;
  bf16* la0 = sA + (size_t)t * 8;
  bf16* la1 = sA + (size_t)(t + 256) * 8;
  bf16* lb0 = sB + (size_t)t * 8;
  bf16* lb1 = sB + (size_t)(t + 256) * 8;
  int wm = (w >> 1) << 6, wn = (w & 1) << 6;
  int row = lane & 15, quad = lane >> 4;
  f32x4 acc[4][4];
#pragma unroll
  for (int i = 0; i < 4; ++i)
#pragma unroll
    for (int j = 0; j < 4; ++j) acc[i][j] = (f32x4){0.f, 0.f, 0.f, 0.f};
  for (int s = 0; s < 8; ++s) {
    __syncthreads();
    int ko = s << 5;
    gload_lds16(ga0 + ko, la0);
    gload_lds16(ga1 + ko, la1);
    gload_lds16(gb0 + ko, lb0);
    gload_lds16(gb1 + ko, lb1);
    __syncthreads();
    short8 af[4], bfr[4];
#pragma unroll
    for (int i = 0; i < 4; ++i)
      af[i] = *(const short8*)(sA + (size_t)(wm + i * 16 + row) * 32 + quad * 8);
#pragma unroll
    for (int j = 0; j < 4; ++j)
      bfr[j] = *(const short8*)(sB + (size_t)(wn + j * 16 + row) * 32 + quad * 8);
#pragma unroll
    for (int i = 0; i < 4; ++i)
#pragma unroll
      for (int j = 0; j < 4; ++j)
        acc[i][j] = __builtin_amdgcn_mfma_f32_16x16x32_bf16(af[i], bfr[j], acc[i][j], 0, 0, 0);
  }
  __syncthreads();
  int col = lane & 15;
#pragma unroll
  for (int i = 0; i < 4; ++i)
#pragma unroll
    for (int j = 0; j < 4; ++j)
#pragma unroll
      for (int r = 0; r < 4; ++r)
        sT[(wn + j * 16 + col) * TP + wm + i * 16 + quad * 4 + r] = f2bu(acc[i][j][r]);
  __syncthreads();
  int b = m0 >> 9, mb = m0 & 511;
  int f = t >> 1, half = t & 1;
  const unsigned short* srow = sT + f * TP + half * 64;
  unsigned short* dst = Wh2T + ((size_t)b * 128 + f) * 512 + mb + half * 64;
#pragma unroll
  for (int c = 0; c < 64; c += 8)
    *(short8*)(dst + c) = *(const short8*)(srow + c);
}

// ---------------- k_sb: s1b/s2b from Wh2T ----------------------------------
// grid 16 blocks (per b), 512 threads (per n)
__global__ __launch_bounds__(512) void k_sb(
    const unsigned short* __restrict__ Wh2T, const float* __restrict__ a_out,
    float* __restrict__ s1b, float* __restrict__ s2b) {
  int b = blockIdx.x, m = threadIdx.x;
  float acc1 = 0.f, acc2 = 0.f;
  const unsigned short* wp = Wh2T + (size_t)b * 128 * 512 + m;
  for (int f = 0; f < 128; ++f) {
    float v = bu2f(wp[(size_t)f * 512]);
    acc1 += v * a_out[f];
    acc2 += v * a_out[128 + f];
  }
  s1b[b * 512 + m] = acc1;
  s2b[b * 512 + m] = acc2;
}

// ---------------- k_attn2_mfma: softmax + att@Wh2 -> elu -> @Wc -> out ------
// grid: b*16 + rb (256 blocks), 256 threads = 4 waves
__global__ __launch_bounds__(256) void k_attn2_mfma(
    const int* __restrict__ adj, const unsigned short* __restrict__ Wh2T,
    const float* __restrict__ s1b, const float* __restrict__ s2b,
    const unsigned short* __restrict__ WcT, const float* __restrict__ bc,
    float* __restrict__ out) {
  int blk = blockIdx.x;
  int rb = blk & 15, b = blk >> 4;
  int t = threadIdx.x, w = t >> 6, lane = t & 63;
  __shared__ unsigned short satt[32 * ATTP];
  __shared__ unsigned short sorow[32 * TP];
  int n0 = rb * 32;
  size_t bb = (size_t)b * 512;

  float s2c[8];
  {
    const float4* sp = (const float4*)(s2b + bb + lane * 8);
    float4 v0 = sp[0], v1 = sp[1];
    s2c[0] = v0.x; s2c[1] = v0.y; s2c[2] = v0.z; s2c[3] = v0.w;
    s2c[4] = v1.x; s2c[5] = v1.y; s2c[6] = v1.z; s2c[7] = v1.w;
  }
  for (int rr = 0; rr < 8; ++rr) {
    int rl = w * 8 + rr;
    int n = n0 + rl;
    float s1v = s1b[bb + n];
    const int* ap = adj + (size_t)b * 262144 + (size_t)n * 512 + lane * 8;
    int4 a0 = *(const int4*)ap;
    int4 a1 = *(const int4*)(ap + 4);
    float e[8];
    e[0] = a0.x > 0 ? lrelu(s1v + s2c[0]) : NEG_;
    e[1] = a0.y > 0 ? lrelu(s1v + s2c[1]) : NEG_;
    e[2] = a0.z > 0 ? lrelu(s1v + s2c[2]) : NEG_;
    e[3] = a0.w > 0 ? lrelu(s1v + s2c[3]) : NEG_;
    e[4] = a1.x > 0 ? lrelu(s1v + s2c[4]) : NEG_;
    e[5] = a1.y > 0 ? lrelu(s1v + s2c[5]) : NEG_;
    e[6] = a1.z > 0 ? lrelu(s1v + s2c[6]) : NEG_;
    e[7] = a1.w > 0 ? lrelu(s1v + s2c[7]) : NEG_;
    float mx = e[0];
#pragma unroll
    for (int k = 1; k < 8; ++k) mx = fmaxf(mx, e[k]);
#pragma unroll
    for (int o = 32; o > 0; o >>= 1) mx = fmaxf(mx, __shfl_xor(mx, o));
    float x[8], sm = 0.f;
#pragma unroll
    for (int k = 0; k < 8; ++k) { x[k] = expf(e[k] - mx); sm += x[k]; }
#pragma unroll
    for (int o = 32; o > 0; o >>= 1) sm += __shfl_xor(sm, o);
    float inv = 1.f / sm;
    short8 st;
#pragma unroll
    for (int k = 0; k < 8; ++k) st[k] = (short)f2bu(x[k] * inv);
    *(short8*)(satt + rl * ATTP + lane * 8) = st;
  }
  __syncthreads();

  // stage A: hp2 = att @ Wh2 (128 f). wave w -> f blocks w and w+4.
  int row = lane & 15, quad = lane >> 4, col = lane & 15;
  f32x4 acc[2][2];
  acc[0][0] = (f32x4){0.f, 0.f, 0.f, 0.f}; acc[0][1] = acc[0][0];
  acc[1][0] = acc[0][0]; acc[1][1] = acc[0][0];
  int f0a = w * 16, f0b = (w + 4) * 16;
  const unsigned short* wpa = Wh2T + ((size_t)b * 128 + f0a + row) * 512 + quad * 8;
  const unsigned short* wpb = Wh2T + ((size_t)b * 128 + f0b + row) * 512 + quad * 8;
#pragma unroll
  for (int kk = 0; kk < 16; ++kk) {
    short8 ba = *(const short8*)(wpa + kk * 32);
    short8 bb2 = *(const short8*)(wpb + kk * 32);
    short8 af0 = *(const short8*)(satt + row * ATTP + kk * 32 + quad * 8);
    short8 af1 = *(const short8*)(satt + (16 + row) * ATTP + kk * 32 + quad * 8);
    acc[0][0] = __builtin_amdgcn_mfma_f32_16x16x32_bf16(af0, ba, acc[0][0], 0, 0, 0);
    acc[0][1] = __builtin_amdgcn_mfma_f32_16x16x32_bf16(af0, bb2, acc[0][1], 0, 0, 0);
    acc[1][0] = __builtin_amdgcn_mfma_f32_16x16x32_bf16(af1, ba, acc[1][0], 0, 0, 0);
    acc[1][1] = __builtin_amdgcn_mfma_f32_16x16x32_bf16(af1, bb2, acc[1][1], 0, 0, 0);
  }
#pragma unroll
  for (int rg = 0; rg < 2; ++rg)
#pragma unroll
    for (int jb = 0; jb < 2; ++jb) {
      int f0 = (w + jb * 4) * 16;
#pragma unroll
      for (int r = 0; r < 4; ++r)
        sorow[(rg * 16 + quad * 4 + r) * TP + f0 + col] = f2bu(eluf(acc[rg][jb][r]));
    }
  __syncthreads();

  // stage B: C = lrelu(orow @ Wc + bc) -> out (atoms section)
  f32x4 c2[2][2];
  c2[0][0] = (f32x4){0.f, 0.f, 0.f, 0.f}; c2[0][1] = c2[0][0];
  c2[1][0] = c2[0][0]; c2[1][1] = c2[0][0];
  const unsigned short* wca = WcT + (size_t)(f0a + row) * 128 + quad * 8;
  const unsigned short* wcb = WcT + (size_t)(f0b + row) * 128 + quad * 8;
#pragma unroll
  for (int kk = 0; kk < 4; ++kk) {
    short8 ba = *(const short8*)(wca + kk * 32);
    short8 bb2 = *(const short8*)(wcb + kk * 32);
    short8 af0 = *(const short8*)(sorow + row * TP + kk * 32 + quad * 8);
    short8 af1 = *(const short8*)(sorow + (16 + row) * TP + kk * 32 + quad * 8);
    c2[0][0] = __builtin_amdgcn_mfma_f32_16x16x32_bf16(af0, ba, c2[0][0], 0, 0, 0);
    c2[0][1] = __builtin_amdgcn_mfma_f32_16x16x32_bf16(af0, bb2, c2[0][1], 0, 0, 0);
    c2[1][0] = __builtin_amdgcn_mfma_f32_16x16x32_bf16(af1, ba, c2[1][0], 0, 0, 0);
    c2[1][1] = __builtin_amdgcn_mfma_f32_16x16x32_bf16(af1, bb2, c2[1][1], 0, 0, 0);
  }
#pragma unroll
  for (int rg = 0; rg < 2; ++rg)
#pragma unroll
    for (int jb = 0; jb < 2; ++jb) {
      int c = (w + jb * 4) * 16 + col;
      float bcv = bc[c];
#pragma unroll
      for (int r = 0; r < 4; ++r) {
        int n = n0 + rg * 16 + quad * 4 + r;
        out[((size_t)b * 1536 + n) * 128 + c] = lrelu(c2[rg][jb][r] + bcv);
      }
    }
}

extern "C" void kernel_launch(void* const* d_in, const int* in_sizes, int n_in,
                              void* d_out, int out_size, void* d_ws, size_t ws_size,
                              hipStream_t stream) {
  const int* atoms = (const int*)d_in[0];
  const int* adj = (const int*)d_in[1];
  const float* prot = (const float*)d_in[3];
  const float* emb_atom = (const float*)d_in[5];
  const float* W_gat = (const float*)d_in[6];
  const float* a_gat = (const float*)d_in[7];
  const float* W_out = (const float*)d_in[8];
  const float* a_out = (const float*)d_in[9];
  const float* Wc = (const float*)d_in[10];
  const float* bc = (const float*)d_in[11];
  const float* W1 = (const float*)d_in[12];
  const float* b1 = (const float*)d_in[13];
  const float* W2 = (const float*)d_in[14];
  const float* b2 = (const float*)d_in[15];
  float* out = (float*)d_out;

  char* p = (char*)d_ws;
  bf16* prot16 = (bf16*)p;        p += (size_t)16384 * 1152 * 2;
  bf16* W1T = (bf16*)p;           p += (size_t)512 * 1152 * 2;
  bf16* W2T = (bf16*)p;           p += (size_t)128 * 512 * 2;
  bf16* W_outT = (bf16*)p;        p += (size_t)128 * 256 * 2;
  bf16* WcT = (bf16*)p;           p += (size_t)128 * 128 * 2;
  bf16* hidp = (bf16*)p;          p += (size_t)16384 * 512 * 2;
  unsigned short* WhT = (unsigned short*)p;      p += (size_t)64 * 64 * 512 * 2;
  unsigned short* multi_bf = (unsigned short*)p; p += (size_t)16 * 512 * 256 * 2;
  unsigned short* Wh2T = (unsigned short*)p;     p += (size_t)16 * 128 * 512 * 2;
  float* s1 = (float*)p;          p += 64 * 512 * 4;
  float* s2 = (float*)p;          p += 64 * 512 * 4;
  float* s1b = (float*)p;         p += 16 * 512 * 4;
  float* s2b = (float*)p;         p += 16 * 512 * 4;
  unsigned short* tab_wh = (unsigned short*)p;   p += 64 * 1024;
  float* tab_s1 = (float*)p;      p += 4096;
  float* tab_s2 = (float*)p;      p += 4096;

  // protein path
  long n4 = (long)16384 * 1152 / 4;
  k_cvt<<<(int)((n4 + 255) / 256), 256, 0, stream>>>(prot, (unsigned short*)prot16, n4);
  k_cvtT<<<(1152 * 512 + 255) / 256, 256, 0, stream>>>(W1, (unsigned short*)W1T, 1152, 512);
  k_cvtT<<<(512 * 128 + 255) / 256, 256, 0, stream>>>(W2, (unsigned short*)W2T, 512, 128);
  k_cvtT<<<(256 * 128 + 255) / 256, 256, 0, stream>>>(W_out, (unsigned short*)W_outT, 256, 128);
  k_cvtT<<<(128 * 128 + 255) / 256, 256, 0, stream>>>(Wc, (unsigned short*)WcT, 128, 128);
  k_gemm_lds<0><<<(16384 / 128) * (512 / 128), 256, 0, stream>>>(prot16, W1T, b1, hidp, 16384, 512, 1152);
  k_gemm_lds<1><<<(16384 / 128) * (128 / 128), 256, 0, stream>>>(hidp, W2T, b2, out, 16384, 128, 512);

  // GAT path (MFMA)
  k_tab<<<45, 256, 0, stream>>>(emb_atom, W_gat, a_gat, tab_wh, tab_s1, tab_s2);
  k_gather<<<64, 256, 0, stream>>>(atoms, tab_wh, tab_s1, tab_s2, WhT, s1, s2);
  k_attn1_mfma<<<1024, 256, 0, stream>>>(adj, WhT, s1, s2, multi_bf);
  k_wh2t<<<64, 256, 0, stream>>>((const bf16*)multi_bf, W_outT, Wh2T);
  k_sb<<<16, 512, 0, stream>>>(Wh2T, a_out, s1b, s2b);
  k_attn2_mfma<<<256, 256, 0, stream>>>(adj, Wh2T, s1b, s2b, (const unsigned short*)WcT, bc, out);

  (void)in_sizes; (void)n_in; (void)out_size; (void)ws_size;
}

// Round 5
// 262.433 us; speedup vs baseline: 2.0269x; 1.0772x over previous
//
#include <hip/hip_runtime.h>
#include <hip/hip_bf16.h>

#define ALPHA_ 0.2f
#define NEG_ -9e15f

typedef __attribute__((ext_vector_type(8))) short short8;
typedef __attribute__((ext_vector_type(4))) float f32x4;
typedef __hip_bfloat16 bf16;

__device__ __forceinline__ float lrelu(float x) { return x > 0.f ? x : ALPHA_ * x; }
__device__ __forceinline__ float eluf(float x) { return x > 0.f ? x : expf(x) - 1.f; }
__device__ __forceinline__ unsigned short f2bu(float x) {
  bf16 h = __float2bfloat16(x);
  return *reinterpret_cast<unsigned short*>(&h);
}
__device__ __forceinline__ float bu2f(unsigned short u) {
  bf16 h = *reinterpret_cast<bf16*>(&u);
  return __bfloat162float(h);
}
__device__ __forceinline__ void gload_lds16(const void* g, void* l) {
  __builtin_amdgcn_global_load_lds((const __attribute__((address_space(1))) void*)g,
                                   (__attribute__((address_space(3))) void*)l,
                                   16, 0, 0);
}

// ---------------- k_cvtw: all weight transposes+converts in one launch ------
// seg layout: W1T[512x1152], W2T[128x512], W_outT[128x256], WcT[128x128]
__global__ void k_cvtw(const float* __restrict__ W1, const float* __restrict__ W2,
                       const float* __restrict__ W_out, const float* __restrict__ Wc,
                       unsigned short* __restrict__ W1T, unsigned short* __restrict__ W2T,
                       unsigned short* __restrict__ W_outT, unsigned short* __restrict__ WcT) {
  long id = (long)blockIdx.x * 256 + threadIdx.x;
  if (id < 589824) {  // W1: R=1152 C=512
    int c = (int)(id / 1152), r = (int)(id % 1152);
    W1T[id] = f2bu(W1[(size_t)r * 512 + c]);
    return;
  }
  id -= 589824;
  if (id < 65536) {   // W2: R=512 C=128
    int c = (int)(id / 512), r = (int)(id % 512);
    W2T[id] = f2bu(W2[(size_t)r * 128 + c]);
    return;
  }
  id -= 65536;
  if (id < 32768) {   // W_out: R=256 C=128
    int c = (int)(id / 256), r = (int)(id % 256);
    W_outT[id] = f2bu(W_out[(size_t)r * 128 + c]);
    return;
  }
  id -= 32768;
  if (id < 16384) {   // Wc: R=128 C=128
    int c = (int)(id / 128), r = (int)(id % 128);
    WcT[id] = f2bu(Wc[(size_t)r * 128 + c]);
  }
}

// ---------------- k_mlp: fused protein MLP ----------------------------------
// grid 256 blocks (64-row strips of M=16384), 256 threads = 4 waves.
// GEMM1: hid = relu(prot@W1+b1) -> LDS bf16 (64x512). GEMM2: lrelu(hid@W2+b2)
// -> f32 d_out amino section. A staged from f32 via regs; W1T via lds-DMA.
#define SHP 520  // padded hid row stride (bf16 elems)
__global__ __launch_bounds__(256) void k_mlp(
    const float* __restrict__ prot, const bf16* __restrict__ W1T,
    const float* __restrict__ b1, const bf16* __restrict__ W2T,
    const float* __restrict__ b2, float* __restrict__ out) {
  __shared__ bf16 sA[64 * 32];
  __shared__ bf16 sB[512 * 32];
  __shared__ unsigned short sH[64 * SHP];
  int t = threadIdx.x, w = t >> 6, lane = t & 63;
  int m0 = blockIdx.x << 6;
  int r0 = t >> 2, cc = t & 3;
  int row = lane & 15, quad = lane >> 4, col = lane & 15;
  const float* gA = prot + (size_t)(m0 + r0) * 1152 + cc * 8;

  f32x4 acc[4][8];
#pragma unroll
  for (int i = 0; i < 4; ++i)
#pragma unroll
    for (int j = 0; j < 8; ++j) acc[i][j] = (f32x4){0.f, 0.f, 0.f, 0.f};

  for (int s = 0; s < 36; ++s) {
    int ko = s << 5;
    __syncthreads();
#pragma unroll
    for (int ps = 0; ps < 8; ++ps)
      gload_lds16(W1T + (size_t)(ps * 64 + r0) * 1152 + ko + cc * 8,
                  sB + (size_t)(ps * 256 + t) * 8);
    float4 a0 = *(const float4*)(gA + ko);
    float4 a1 = *(const float4*)(gA + ko + 4);
    short8 av;
    av[0] = (short)f2bu(a0.x); av[1] = (short)f2bu(a0.y);
    av[2] = (short)f2bu(a0.z); av[3] = (short)f2bu(a0.w);
    av[4] = (short)f2bu(a1.x); av[5] = (short)f2bu(a1.y);
    av[6] = (short)f2bu(a1.z); av[7] = (short)f2bu(a1.w);
    *(short8*)(sA + (size_t)r0 * 32 + cc * 8) = av;
    __syncthreads();
    short8 af[4];
#pragma unroll
    for (int i = 0; i < 4; ++i)
      af[i] = *(const short8*)(sA + (size_t)(i * 16 + row) * 32 + quad * 8);
#pragma unroll
    for (int j = 0; j < 8; ++j) {
      short8 bfr = *(const short8*)(sB + (size_t)(w * 128 + j * 16 + row) * 32 + quad * 8);
#pragma unroll
      for (int i = 0; i < 4; ++i)
        acc[i][j] = __builtin_amdgcn_mfma_f32_16x16x32_bf16(af[i], bfr, acc[i][j], 0, 0, 0);
    }
  }
  __syncthreads();
  // epilogue1: relu -> sH bf16
#pragma unroll
  for (int j = 0; j < 8; ++j) {
    int n = w * 128 + j * 16 + col;
    float bv = b1[n];
#pragma unroll
    for (int i = 0; i < 4; ++i)
#pragma unroll
      for (int r = 0; r < 4; ++r) {
        int m = i * 16 + quad * 4 + r;
        float v = acc[i][j][r] + bv;
        sH[(size_t)m * SHP + n] = f2bu(v > 0.f ? v : 0.f);
      }
  }
  __syncthreads();
  // GEMM2: out = lrelu(hid @ W2 + b2), wave w -> n range [w*32, w*32+32)
  f32x4 acc2[4][2];
#pragma unroll
  for (int i = 0; i < 4; ++i) {
    acc2[i][0] = (f32x4){0.f, 0.f, 0.f, 0.f};
    acc2[i][1] = acc2[i][0];
  }
  for (int s = 0; s < 16; ++s) {
    int ko = s << 5;
    short8 b0 = *(const short8*)(W2T + (size_t)(w * 32 + row) * 512 + ko + quad * 8);
    short8 b1f = *(const short8*)(W2T + (size_t)(w * 32 + 16 + row) * 512 + ko + quad * 8);
#pragma unroll
    for (int i = 0; i < 4; ++i) {
      short8 a2 = *(const short8*)(sH + (size_t)(i * 16 + row) * SHP + ko + quad * 8);
      acc2[i][0] = __builtin_amdgcn_mfma_f32_16x16x32_bf16(a2, b0, acc2[i][0], 0, 0, 0);
      acc2[i][1] = __builtin_amdgcn_mfma_f32_16x16x32_bf16(a2, b1f, acc2[i][1], 0, 0, 0);
    }
  }
#pragma unroll
  for (int jb = 0; jb < 2; ++jb) {
    int n = w * 32 + jb * 16 + col;
    float bv = b2[n];
#pragma unroll
    for (int i = 0; i < 4; ++i)
#pragma unroll
      for (int r = 0; r < 4; ++r) {
        int m = m0 + i * 16 + quad * 4 + r;
        float v = lrelu(acc2[i][jb][r] + bv);
        int b = m >> 10, l = m & 1023;
        out[((size_t)b * 1536 + 512 + l) * 128 + n] = v;
      }
  }
}

// ---------------- k_tab: per-atom-type Wh table (45 types) ------------------
__global__ __launch_bounds__(256) void k_tab(
    const float* __restrict__ emb_atom, const float* __restrict__ W_gat,
    const float* __restrict__ a_gat, unsigned short* __restrict__ tab_wh,
    float* __restrict__ tab_s1, float* __restrict__ tab_s2) {
  int a = blockIdx.x;
  int t = threadIdx.x;
  __shared__ float av[128];
  __shared__ float whl[256];
  if (t < 128) av[t] = emb_atom[a * 128 + t];
  __syncthreads();
  int h = t >> 6, f = t & 63;
  const float* Wg = W_gat + h * 128 * 64 + f;
  float acc = 0.f;
#pragma unroll 8
  for (int c = 0; c < 128; ++c) acc += av[c] * Wg[c * 64];
  whl[t] = acc;
  tab_wh[a * 256 + t] = f2bu(acc);
  __syncthreads();
  if (t < 8) {
    int hh = t >> 1, which = t & 1;
    float s = 0.f;
    for (int ff = 0; ff < 64; ++ff)
      s += whl[hh * 64 + ff] * a_gat[hh * 128 + which * 64 + ff];
    if (which == 0) tab_s1[a * 4 + hh] = s; else tab_s2[a * 4 + hh] = s;
  }
}

// ---------------- k_gather: WhT[b,h,f,n], s1[b,h,n], s2 ---------------------
__global__ __launch_bounds__(256) void k_gather(
    const int* __restrict__ atoms, const unsigned short* __restrict__ tab_wh,
    const float* __restrict__ tab_s1, const float* __restrict__ tab_s2,
    unsigned short* __restrict__ WhT, float* __restrict__ s1,
    float* __restrict__ s2) {
  int bh = blockIdx.x;
  int b = bh >> 2, h = bh & 3;
  int t = threadIdx.x;
  __shared__ int atom_l[512];
  __shared__ unsigned short tabL[45 * 64];
  atom_l[t] = atoms[b * 512 + t];
  atom_l[t + 256] = atoms[b * 512 + t + 256];
  for (int i = t; i < 45 * 64; i += 256)
    tabL[i] = tab_wh[(i >> 6) * 256 + h * 64 + (i & 63)];
  __syncthreads();
  {
    int n = t;
    s1[(size_t)bh * 512 + n] = tab_s1[atom_l[n] * 4 + h];
    s2[(size_t)bh * 512 + n] = tab_s2[atom_l[n] * 4 + h];
    n = t + 256;
    s1[(size_t)bh * 512 + n] = tab_s1[atom_l[n] * 4 + h];
    s2[(size_t)bh * 512 + n] = tab_s2[atom_l[n] * 4 + h];
  }
  for (int f = 0; f < 64; ++f) {
    WhT[((size_t)bh * 64 + f) * 512 + t] = tabL[atom_l[t] * 64 + f];
    WhT[((size_t)bh * 64 + f) * 512 + t + 256] = tabL[atom_l[t + 256] * 64 + f];
  }
}

// ---------------- k_attn1_mfma: softmax + MFMA att@Wh -> multi (bf16) -------
#define ATTP 520
__global__ __launch_bounds__(256) void k_attn1_mfma(
    const int* __restrict__ adj, const unsigned short* __restrict__ WhT,
    const float* __restrict__ s1, const float* __restrict__ s2,
    unsigned short* __restrict__ multi_bf) {
  int blk = blockIdx.x;
  int rb = blk & 15, h = (blk >> 4) & 3, b = blk >> 6;
  int t = threadIdx.x, w = t >> 6, lane = t & 63;
  __shared__ unsigned short satt[32 * ATTP];
  int n0 = rb * 32;
  size_t bh = ((size_t)b * 4 + h) * 512;

  float s2c[8];
  {
    const float4* sp = (const float4*)(s2 + bh + lane * 8);
    float4 v0 = sp[0], v1 = sp[1];
    s2c[0] = v0.x; s2c[1] = v0.y; s2c[2] = v0.z; s2c[3] = v0.w;
    s2c[4] = v1.x; s2c[5] = v1.y; s2c[6] = v1.z; s2c[7] = v1.w;
  }
  for (int rr = 0; rr < 8; ++rr) {
    int rl = w * 8 + rr;
    int n = n0 + rl;
    float s1v = s1[bh + n];
    const int* ap = adj + (size_t)b * 262144 + (size_t)n * 512 + lane * 8;
    int4 a0 = *(const int4*)ap;
    int4 a1 = *(const int4*)(ap + 4);
    float e[8];
    e[0] = a0.x > 0 ? lrelu(s1v + s2c[0]) : NEG_;
    e[1] = a0.y > 0 ? lrelu(s1v + s2c[1]) : NEG_;
    e[2] = a0.z > 0 ? lrelu(s1v + s2c[2]) : NEG_;
    e[3] = a0.w > 0 ? lrelu(s1v + s2c[3]) : NEG_;
    e[4] = a1.x > 0 ? lrelu(s1v + s2c[4]) : NEG_;
    e[5] = a1.y > 0 ? lrelu(s1v + s2c[5]) : NEG_;
    e[6] = a1.z > 0 ? lrelu(s1v + s2c[6]) : NEG_;
    e[7] = a1.w > 0 ? lrelu(s1v + s2c[7]) : NEG_;
    float mx = e[0];
#pragma unroll
    for (int k = 1; k < 8; ++k) mx = fmaxf(mx, e[k]);
#pragma unroll
    for (int o = 32; o > 0; o >>= 1) mx = fmaxf(mx, __shfl_xor(mx, o));
    float x[8], sm = 0.f;
#pragma unroll
    for (int k = 0; k < 8; ++k) { x[k] = expf(e[k] - mx); sm += x[k]; }
#pragma unroll
    for (int o = 32; o > 0; o >>= 1) sm += __shfl_xor(sm, o);
    float inv = 1.f / sm;
    short8 st;
#pragma unroll
    for (int k = 0; k < 8; ++k) st[k] = (short)f2bu(x[k] * inv);
    *(short8*)(satt + rl * ATTP + lane * 8) = st;
  }
  __syncthreads();

  int row = lane & 15, quad = lane >> 4;
  int f0 = w * 16;
  f32x4 acc0 = {0.f, 0.f, 0.f, 0.f}, acc1 = {0.f, 0.f, 0.f, 0.f};
  const unsigned short* wp = WhT + ((size_t)(b * 4 + h) * 64 + f0 + row) * 512 + quad * 8;
#pragma unroll
  for (int kk = 0; kk < 16; ++kk) {
    short8 bfr = *(const short8*)(wp + kk * 32);
    short8 af0 = *(const short8*)(satt + row * ATTP + kk * 32 + quad * 8);
    short8 af1 = *(const short8*)(satt + (16 + row) * ATTP + kk * 32 + quad * 8);
    acc0 = __builtin_amdgcn_mfma_f32_16x16x32_bf16(af0, bfr, acc0, 0, 0, 0);
    acc1 = __builtin_amdgcn_mfma_f32_16x16x32_bf16(af1, bfr, acc1, 0, 0, 0);
  }
  int col = lane & 15;
#pragma unroll
  for (int r = 0; r < 4; ++r) {
    int f = f0 + col;
    int m = n0 + quad * 4 + r;
    multi_bf[((size_t)b * 512 + m) * 256 + h * 64 + f] = f2bu(eluf(acc0[r]));
    m = n0 + 16 + quad * 4 + r;
    multi_bf[((size_t)b * 512 + m) * 256 + h * 64 + f] = f2bu(eluf(acc1[r]));
  }
}

// ---------------- k_wh2t: Wh2T = (multi @ W_out)^T bf16, + s1b/s2b ----------
#define TP 136
__global__ __launch_bounds__(256) void k_wh2t(
    const bf16* __restrict__ A, const bf16* __restrict__ Bt,
    const float* __restrict__ a_out, unsigned short* __restrict__ Wh2T,
    float* __restrict__ s1b, float* __restrict__ s2b) {
  __shared__ bf16 sA[128 * 32];
  __shared__ bf16 sB[128 * 32];
  __shared__ unsigned short sT[128 * TP];
  __shared__ float sao[256];
  const int K = 256;
  int t = threadIdx.x;
  int w = t >> 6, lane = t & 63;
  int m0 = blockIdx.x << 7;
  sao[t] = a_out[t];
  int r0 = t >> 2, cc = t & 3;
  const bf16* ga0 = A + (size_t)(m0 + r0) * K + cc * 8;
  const bf16* ga1 = A + (size_t)(m0 + r0 + 64) * K + cc * 8;
  const bf16* gb0 = Bt + (size_t)r0 * K + cc * 8;
  const bf16* gb1 = Bt + (size_t)(r0 + 64) * K + cc * 8;
  bf16* la0 = sA + (size_t)t * 8;
  bf16* la1 = sA + (size_t)(t + 256) * 8;
  bf16* lb0 = sB + (size_t)t * 8;
  bf16* lb1 = sB + (size_t)(t + 256) * 8;
  int wm = (w >> 1) << 6, wn = (w & 1) << 6;
  int row = lane & 15, quad = lane >> 4;
  f32x4 acc[4][4];
#pragma unroll
  for (int i = 0; i < 4; ++i)
#pragma unroll
    for (int j = 0; j < 4; ++j) acc[i][j] = (f32x4){0.f, 0.f, 0.f, 0.f};
  for (int s = 0; s < 8; ++s) {
    __syncthreads();
    int ko = s << 5;
    gload_lds16(ga0 + ko, la0);
    gload_lds16(ga1 + ko, la1);
    gload_lds16(gb0 + ko, lb0);
    gload_lds16(gb1 + ko, lb1);
    __syncthreads();
    short8 af[4], bfr[4];
#pragma unroll
    for (int i = 0; i < 4; ++i)
      af[i] = *(const short8*)(sA + (size_t)(wm + i * 16 + row) * 32 + quad * 8);
#pragma unroll
    for (int j = 0; j < 4; ++j)
      bfr[j] = *(const short8*)(sB + (size_t)(wn + j * 16 + row) * 32 + quad * 8);
#pragma unroll
    for (int i = 0; i < 4; ++i)
#pragma unroll
      for (int j = 0; j < 4; ++j)
        acc[i][j] = __builtin_amdgcn_mfma_f32_16x16x32_bf16(af[i], bfr[j], acc[i][j], 0, 0, 0);
  }
  __syncthreads();
  int col = lane & 15;
#pragma unroll
  for (int i = 0; i < 4; ++i)
#pragma unroll
    for (int j = 0; j < 4; ++j)
#pragma unroll
      for (int r = 0; r < 4; ++r)
        sT[(wn + j * 16 + col) * TP + wm + i * 16 + quad * 4 + r] = f2bu(acc[i][j][r]);
  __syncthreads();
  int b = m0 >> 9, mb = m0 & 511;
  {
    int f = t >> 1, half = t & 1;
    const unsigned short* srow = sT + f * TP + half * 64;
    unsigned short* dst = Wh2T + ((size_t)b * 128 + f) * 512 + mb + half * 64;
#pragma unroll
    for (int c = 0; c < 64; c += 8)
      *(short8*)(dst + c) = *(const short8*)(srow + c);
  }
  if (t < 128) {
    float acc1 = 0.f, acc2 = 0.f;
#pragma unroll 4
    for (int f = 0; f < 128; ++f) {
      float v = bu2f(sT[f * TP + t]);
      acc1 += v * sao[f];
      acc2 += v * sao[128 + f];
    }
    s1b[b * 512 + mb + t] = acc1;
    s2b[b * 512 + mb + t] = acc2;
  }
}

// ---------------- k_attn2_mfma: softmax + att@Wh2 -> elu -> @Wc -> out ------
__global__ __launch_bounds__(256) void k_attn2_mfma(
    const int* __restrict__ adj, const unsigned short* __restrict__ Wh2T,
    const float* __restrict__ s1b, const float* __restrict__ s2b,
    const unsigned short* __restrict__ WcT, const float* __restrict__ bc,
    float* __restrict__ out) {
  int blk = blockIdx.x;
  int rb = blk & 15, b = blk >> 4;
  int t = threadIdx.x, w = t >> 6, lane = t & 63;
  __shared__ unsigned short satt[32 * ATTP];
  __shared__ unsigned short sorow[32 * TP];
  int n0 = rb * 32;
  size_t bb = (size_t)b * 512;

  float s2c[8];
  {
    const float4* sp = (const float4*)(s2b + bb + lane * 8);
    float4 v0 = sp[0], v1 = sp[1];
    s2c[0] = v0.x; s2c[1] = v0.y; s2c[2] = v0.z; s2c[3] = v0.w;
    s2c[4] = v1.x; s2c[5] = v1.y; s2c[6] = v1.z; s2c[7] = v1.w;
  }
  for (int rr = 0; rr < 8; ++rr) {
    int rl = w * 8 + rr;
    int n = n0 + rl;
    float s1v = s1b[bb + n];
    const int* ap = adj + (size_t)b * 262144 + (size_t)n * 512 + lane * 8;
    int4 a0 = *(const int4*)ap;
    int4 a1 = *(const int4*)(ap + 4);
    float e[8];
    e[0] = a0.x > 0 ? lrelu(s1v + s2c[0]) : NEG_;
    e[1] = a0.y > 0 ? lrelu(s1v + s2c[1]) : NEG_;
    e[2] = a0.z > 0 ? lrelu(s1v + s2c[2]) : NEG_;
    e[3] = a0.w > 0 ? lrelu(s1v + s2c[3]) : NEG_;
    e[4] = a1.x > 0 ? lrelu(s1v + s2c[4]) : NEG_;
    e[5] = a1.y > 0 ? lrelu(s1v + s2c[5]) : NEG_;
    e[6] = a1.z > 0 ? lrelu(s1v + s2c[6]) : NEG_;
    e[7] = a1.w > 0 ? lrelu(s1v + s2c[7]) : NEG_;
    float mx = e[0];
#pragma unroll
    for (int k = 1; k < 8; ++k) mx = fmaxf(mx, e[k]);
#pragma unroll
    for (int o = 32; o > 0; o >>= 1) mx = fmaxf(mx, __shfl_xor(mx, o));
    float x[8], sm = 0.f;
#pragma unroll
    for (int k = 0; k < 8; ++k) { x[k] = expf(e[k] - mx); sm += x[k]; }
#pragma unroll
    for (int o = 32; o > 0; o >>= 1) sm += __shfl_xor(sm, o);
    float inv = 1.f / sm;
    short8 st;
#pragma unroll
    for (int k = 0; k < 8; ++k) st[k] = (short)f2bu(x[k] * inv);
    *(short8*)(satt + rl * ATTP + lane * 8) = st;
  }
  __syncthreads();

  int row = lane & 15, quad = lane >> 4, col = lane & 15;
  f32x4 acc[2][2];
  acc[0][0] = (f32x4){0.f, 0.f, 0.f, 0.f}; acc[0][1] = acc[0][0];
  acc[1][0] = acc[0][0]; acc[1][1] = acc[0][0];
  int f0a = w * 16, f0b = (w + 4) * 16;
  const unsigned short* wpa = Wh2T + ((size_t)b * 128 + f0a + row) * 512 + quad * 8;
  const unsigned short* wpb = Wh2T + ((size_t)b * 128 + f0b + row) * 512 + quad * 8;
#pragma unroll
  for (int kk = 0; kk < 16; ++kk) {
    short8 ba = *(const short8*)(wpa + kk * 32);
    short8 bb2 = *(const short8*)(wpb + kk * 32);
    short8 af0 = *(const short8*)(satt + row * ATTP + kk * 32 + quad * 8);
    short8 af1 = *(const short8*)(satt + (16 + row) * ATTP + kk * 32 + quad * 8);
    acc[0][0] = __builtin_amdgcn_mfma_f32_16x16x32_bf16(af0, ba, acc[0][0], 0, 0, 0);
    acc[0][1] = __builtin_amdgcn_mfma_f32_16x16x32_bf16(af0, bb2, acc[0][1], 0, 0, 0);
    acc[1][0] = __builtin_amdgcn_mfma_f32_16x16x32_bf16(af1, ba, acc[1][0], 0, 0, 0);
    acc[1][1] = __builtin_amdgcn_mfma_f32_16x16x32_bf16(af1, bb2, acc[1][1], 0, 0, 0);
  }
#pragma unroll
  for (int rg = 0; rg < 2; ++rg)
#pragma unroll
    for (int jb = 0; jb < 2; ++jb) {
      int f0 = (w + jb * 4) * 16;
#pragma unroll
      for (int r = 0; r < 4; ++r)
        sorow[(rg * 16 + quad * 4 + r) * TP + f0 + col] = f2bu(eluf(acc[rg][jb][r]));
    }
  __syncthreads();

  f32x4 c2[2][2];
  c2[0][0] = (f32x4){0.f, 0.f, 0.f, 0.f}; c2[0][1] = c2[0][0];
  c2[1][0] = c2[0][0]; c2[1][1] = c2[0][0];
  const unsigned short* wca = WcT + (size_t)(f0a + row) * 128 + quad * 8;
  const unsigned short* wcb = WcT + (size_t)(f0b + row) * 128 + quad * 8;
#pragma unroll
  for (int kk = 0; kk < 4; ++kk) {
    short8 ba = *(const short8*)(wca + kk * 32);
    short8 bb2 = *(const short8*)(wcb + kk * 32);
    short8 af0 = *(const short8*)(sorow + row * TP + kk * 32 + quad * 8);
    short8 af1 = *(const short8*)(sorow + (16 + row) * TP + kk * 32 + quad * 8);
    c2[0][0] = __builtin_amdgcn_mfma_f32_16x16x32_bf16(af0, ba, c2[0][0], 0, 0, 0);
    c2[0][1] = __builtin_amdgcn_mfma_f32_16x16x32_bf16(af0, bb2, c2[0][1], 0, 0, 0);
    c2[1][0] = __builtin_amdgcn_mfma_f32_16x16x32_bf16(af1, ba, c2[1][0], 0, 0, 0);
    c2[1][1] = __builtin_amdgcn_mfma_f32_16x16x32_bf16(af1, bb2, c2[1][1], 0, 0, 0);
  }
#pragma unroll
  for (int rg = 0; rg < 2; ++rg)
#pragma unroll
    for (int jb = 0; jb < 2; ++jb) {
      int c = (w + jb * 4) * 16 + col;
      float bcv = bc[c];
#pragma unroll
      for (int r = 0; r < 4; ++r) {
        int n = n0 + rg * 16 + quad * 4 + r;
        out[((size_t)b * 1536 + n) * 128 + c] = lrelu(c2[rg][jb][r] + bcv);
      }
    }
}

extern "C" void kernel_launch(void* const* d_in, const int* in_sizes, int n_in,
                              void* d_out, int out_size, void* d_ws, size_t ws_size,
                              hipStream_t stream) {
  const int* atoms = (const int*)d_in[0];
  const int* adj = (const int*)d_in[1];
  const float* prot = (const float*)d_in[3];
  const float* emb_atom = (const float*)d_in[5];
  const float* W_gat = (const float*)d_in[6];
  const float* a_gat = (const float*)d_in[7];
  const float* W_out = (const float*)d_in[8];
  const float* a_out = (const float*)d_in[9];
  const float* Wc = (const float*)d_in[10];
  const float* bc = (const float*)d_in[11];
  const float* W1 = (const float*)d_in[12];
  const float* b1 = (const float*)d_in[13];
  const float* W2 = (const float*)d_in[14];
  const float* b2 = (const float*)d_in[15];
  float* out = (float*)d_out;

  char* p = (char*)d_ws;
  unsigned short* W1T = (unsigned short*)p;      p += (size_t)512 * 1152 * 2;
  unsigned short* W2T = (unsigned short*)p;      p += (size_t)128 * 512 * 2;
  unsigned short* W_outT = (unsigned short*)p;   p += (size_t)128 * 256 * 2;
  unsigned short* WcT = (unsigned short*)p;      p += (size_t)128 * 128 * 2;
  unsigned short* WhT = (unsigned short*)p;      p += (size_t)64 * 64 * 512 * 2;
  unsigned short* multi_bf = (unsigned short*)p; p += (size_t)16 * 512 * 256 * 2;
  unsigned short* Wh2T = (unsigned short*)p;     p += (size_t)16 * 128 * 512 * 2;
  float* s1 = (float*)p;          p += 64 * 512 * 4;
  float* s2 = (float*)p;          p += 64 * 512 * 4;
  float* s1b = (float*)p;         p += 16 * 512 * 4;
  float* s2b = (float*)p;         p += 16 * 512 * 4;
  unsigned short* tab_wh = (unsigned short*)p;   p += 64 * 1024;
  float* tab_s1 = (float*)p;      p += 4096;
  float* tab_s2 = (float*)p;      p += 4096;

  k_cvtw<<<2752, 256, 0, stream>>>(W1, W2, W_out, Wc, W1T, W2T, W_outT, WcT);
  k_mlp<<<256, 256, 0, stream>>>(prot, (const bf16*)W1T, b1, (const bf16*)W2T, b2, out);

  k_tab<<<45, 256, 0, stream>>>(emb_atom, W_gat, a_gat, tab_wh, tab_s1, tab_s2);
  k_gather<<<64, 256, 0, stream>>>(atoms, tab_wh, tab_s1, tab_s2, WhT, s1, s2);
  k_attn1_mfma<<<1024, 256, 0, stream>>>(adj, WhT, s1, s2, multi_bf);
  k_wh2t<<<64, 256, 0, stream>>>((const bf16*)multi_bf, (const bf16*)W_outT, a_out, Wh2T, s1b, s2b);
  k_attn2_mfma<<<256, 256, 0, stream>>>(adj, Wh2T, s1b, s2b, WcT, bc, out);

  (void)in_sizes; (void)n_in; (void)out_size; (void)ws_size;
}